// Round 1
// baseline (349.181 us; speedup 1.0000x reference)
//
#include <hip/hip_runtime.h>

#define T_TOTAL 3072
#define DET 1024
#define CLIPV 20.0f

// One block = one wave (64 lanes) = one batch element. lane == trellis state.
__global__ __launch_bounds__(64) void cva_decode_kernel(const float* __restrict__ x,
                                                        float* __restrict__ out) {
    const int b    = blockIdx.x;
    const int lane = threadIdx.x;          // state s in [0,64)

    __shared__ float2 lx[DET];                      // staged LLR pairs, 8 KB
    __shared__ unsigned long long dec[T_TOTAL];     // decision masks, 24 KB
    __shared__ unsigned int bitw[DET / 32];         // output bits, 128 B

    // ---- stage this batch row's LLRs: 2048 floats = 1024 float2 ----
    const float2* xrow = reinterpret_cast<const float2*>(x + (size_t)b * (2 * DET));
    for (int i = lane; i < DET; i += 64) lx[i] = xrow[i];
    __syncthreads();

    // ---- per-lane edge code bits (compile-time-ish constants) ----
    // next state s, branch j: prev p = (2s+j)&63, input bit bb = s>>5
    // reg = [bb, p5, p4, p3, p2, p1, p0]
    // GM row0 = [1,1,1,1,0,0,1] -> c0 = bb ^ p5 ^ p4 ^ p3 ^ p0
    // GM row1 = [1,0,1,1,0,1,1] -> c1 = bb ^ p4 ^ p3 ^ p1 ^ p0
    const int s  = lane;
    const int bb = (s >> 5) & 1;
    bool e00, e01, e10, e11;
    {
        int p  = (2 * s) & 63;
        e00 = (bb ^ ((p >> 5) & 1) ^ ((p >> 4) & 1) ^ ((p >> 3) & 1) ^ (p & 1)) != 0;
        e01 = (bb ^ ((p >> 4) & 1) ^ ((p >> 3) & 1) ^ ((p >> 1) & 1) ^ (p & 1)) != 0;
        p  = (2 * s + 1) & 63;
        e10 = (bb ^ ((p >> 5) & 1) ^ ((p >> 4) & 1) ^ ((p >> 3) & 1) ^ (p & 1)) != 0;
        e11 = (bb ^ ((p >> 4) & 1) ^ ((p >> 3) & 1) ^ ((p >> 1) & 1) ^ (p & 1)) != 0;
    }

    const int src0 = (2 * s) & 63;         // shfl source lanes (per-lane constants)
    const int src1 = (2 * s + 1) & 63;

    // ---- forward ACS: 3072 strictly sequential steps ----
    float m = 0.0f;                         // path metric of state s (in_prob0 = 0)
    for (int rep = 0; rep < 3; ++rep) {
        const int tbase = rep * DET;
        #pragma unroll 8
        for (int tm = 0; tm < DET; ++tm) {
            float2 llr = lx[tm];
            // branch metrics via selects: bit-exact vs reference (edge bits are 0/1)
            float B0 = (e00 ? llr.x : 0.0f) + (e01 ? llr.y : 0.0f);
            float B1 = (e10 ? llr.x : 0.0f) + (e11 ? llr.y : 0.0f);
            float v0 = __shfl(m, src0, 64);
            float v1 = __shfl(m, src1, 64);
            float t0 = v0 + B0;
            float t1 = v1 + B1;
            unsigned long long bal = __ballot(t1 < t0);  // argmin: j=1 iff strictly less
            float mn = fminf(t0, t1);
            m = fminf(fmaxf(mn, -CLIPV), CLIPV);         // clip(min(total))
            if (lane == 0) dec[tbase + tm] = bal;
        }
    }
    __syncthreads();

    // ---- traceback (lane 0 only): t = 3071 .. 1024 ----
    if (lane == 0) {
        int st = 0;
        // discard top replication's bits, just follow the path
        #pragma unroll 8
        for (int t = T_TOTAL - 1; t >= 2 * DET; --t) {
            int d = (int)((dec[t] >> st) & 1ull);
            st = ((st << 1) | d) & 63;
        }
        // middle replication: emit bits
        unsigned int acc = 0;
        #pragma unroll 32
        for (int i = DET - 1; i >= 0; --i) {
            unsigned int bit = (~(unsigned)st) & 1u;     // (state+1)%2
            acc |= bit << (i & 31);
            if ((i & 31) == 0) { bitw[i >> 5] = acc; acc = 0; }
            int d = (int)((dec[DET + i] >> st) & 1ull);
            st = ((st << 1) | d) & 63;
        }
    }
    __syncthreads();

    // ---- coalesced output store: 1024 floats per batch ----
    float* orow = out + (size_t)b * DET;
    #pragma unroll
    for (int c = 0; c < 16; ++c) {
        int i = c * 64 + lane;
        unsigned int bit = (bitw[i >> 5] >> (i & 31)) & 1u;
        orow[i] = (float)bit;
    }
}

extern "C" void kernel_launch(void* const* d_in, const int* in_sizes, int n_in,
                              void* d_out, int out_size, void* d_ws, size_t ws_size,
                              hipStream_t stream) {
    const float* x = (const float*)d_in[0];
    float* out = (float*)d_out;
    (void)in_sizes; (void)n_in; (void)d_ws; (void)ws_size; (void)out_size;
    // BATCH = 512 blocks, one wave each
    hipLaunchKernelGGL(cva_decode_kernel, dim3(512), dim3(64), 0, stream, x, out);
}